// Round 1
// baseline (141.807 us; speedup 1.0000x reference)
//
#include <hip/hip_runtime.h>

typedef __attribute__((ext_vector_type(8))) short short8;
typedef __attribute__((ext_vector_type(16))) float f32x16;

#define N_IMG 32
#define C_IN 32
#define C_OUT 32
#define HH 224
#define WW 224
#define HW (HH * WW)
#define TILE_H 8
#define TILE_W 32
#define IN_H (TILE_H + 2)   // 10
#define IN_W (TILE_W + 2)   // 34
#define PIX_STRIDE 80       // bytes/pixel in LDS: 64B data (32ch bf16) + 16B pad (5x16B -> conflict-free)
#define N_HBLK (HH / TILE_H)  // 28
#define N_WBLK (WW / TILE_W)  // 7
#define N_TILES (N_IMG * N_HBLK * N_WBLK)  // 6272

// fp32 -> bf16 bits, round-to-nearest-even (inputs are finite normals; no NaN handling needed)
__device__ __forceinline__ short f2bf(float f) {
    unsigned u = __float_as_uint(f);
    u += 0x7FFFu + ((u >> 16) & 1u);
    return (short)(u >> 16);
}

__global__ __launch_bounds__(256, 3)
void conv3x3_kernel(const float* __restrict__ X, const float* __restrict__ Wt,
                    const float* __restrict__ Bias, float* __restrict__ Y) {
    // input tile: 10 x 34 pixels, 32 bf16 channels each, 80B pixel stride
    __shared__ __align__(16) char xtile[IN_H * IN_W * PIX_STRIDE];  // 27,200 B

    const int tid = threadIdx.x;
    const int lane = tid & 63;
    const int wid = tid >> 6;      // wave 0..3
    const int col = lane & 31;     // A: out-channel row; B: pixel col; C: pixel col
    const int khalf = lane >> 5;   // k-half of the MFMA K=16 slice

    // --- Preload W fragments into registers (A operand: M=32 k_out, K=16 c-slice) ---
    // A[m][k]: m = lane&31 = k_out, k = (lane>>5)*8 + j  (c = ch*16 + khalf*8 + j)
    short8 wfrag[18];
#pragma unroll
    for (int rs = 0; rs < 9; ++rs) {
#pragma unroll
        for (int ch = 0; ch < 2; ++ch) {
            short8 f;
#pragma unroll
            for (int j = 0; j < 8; ++j) {
                int c = ch * 16 + khalf * 8 + j;
                f[j] = f2bf(Wt[(col * C_IN + c) * 9 + rs]);  // W[k_out][c][r][s]
            }
            wfrag[rs * 2 + ch] = f;
        }
    }

    // --- Bias in C-fragment order: row(k_out) = (i&3) + 8*(i>>2) + 4*khalf ---
    f32x16 biasv;
#pragma unroll
    for (int i = 0; i < 16; ++i)
        biasv[i] = Bias[(i & 3) + 8 * (i >> 2) + 4 * khalf];

    for (int tile = blockIdx.x; tile < N_TILES; tile += gridDim.x) {
        int wblk = tile % N_WBLK;
        int t2 = tile / N_WBLK;
        int hblk = t2 % N_HBLK;
        int n = t2 / N_HBLK;
        int h0 = hblk * TILE_H, w0 = wblk * TILE_W;

        __syncthreads();  // previous tile's readers done before overwrite

        // --- Stage input halo tile (fp32 HBM -> bf16 LDS), channel-chunked b128 writes ---
        // chunk id: icol fastest (w-coalesced global loads), then irow, then channel-chunk cc
        for (int cid = tid; cid < IN_H * IN_W * 4; cid += 256) {
            int icol = cid % IN_W;
            int t = cid / IN_W;
            int irow = t % IN_H;
            int cc = t / IN_H;  // channel chunk 0..3 (8 channels each)
            int h_in = h0 - 1 + irow;
            int w_in = w0 - 1 + icol;
            short8 v = {0, 0, 0, 0, 0, 0, 0, 0};
            if ((unsigned)h_in < (unsigned)HH && (unsigned)w_in < (unsigned)WW) {
                const float* p = X + ((n * C_IN + cc * 8) * HH + h_in) * WW + w_in;
#pragma unroll
                for (int j = 0; j < 8; ++j)
                    v[j] = f2bf(p[j * HW]);
            }
            *(short8*)(xtile + (irow * IN_W + icol) * PIX_STRIDE + cc * 16) = v;
        }
        __syncthreads();

        // --- Compute: each wave owns 2 tile rows; per row 18 MFMAs over (r,s,chalf) ---
#pragma unroll
        for (int nb = 0; nb < 2; ++nb) {
            int tr = wid * 2 + nb;
            f32x16 acc = biasv;  // bias folded into accumulator init
#pragma unroll
            for (int rs = 0; rs < 9; ++rs) {
                int r = rs / 3, s = rs - 3 * r;
                // B[k][n]: n = col = output pixel, k-slice channels; input pixel (tr+r, col+s)
                int pixbase = ((tr + r) * IN_W + col + s) * PIX_STRIDE + khalf * 16;
#pragma unroll
                for (int ch = 0; ch < 2; ++ch) {
                    short8 bfrag = *(const short8*)(xtile + pixbase + ch * 32);
                    acc = __builtin_amdgcn_mfma_f32_32x32x16_bf16(
                        wfrag[rs * 2 + ch], bfrag, acc, 0, 0, 0);
                }
            }
            // --- Store: C col = pixel (coalesced 128B per half-wave), rows = k_out ---
            int ybase = (n * C_OUT * HH + (h0 + tr)) * WW + w0 + col;
#pragma unroll
            for (int i = 0; i < 16; ++i) {
                int ko = (i & 3) + 8 * (i >> 2) + 4 * khalf;
                Y[ybase + ko * HW] = acc[i];
            }
        }
    }
}

extern "C" void kernel_launch(void* const* d_in, const int* in_sizes, int n_in,
                              void* d_out, int out_size, void* d_ws, size_t ws_size,
                              hipStream_t stream) {
    const float* X = (const float*)d_in[0];
    const float* W = (const float*)d_in[1];
    const float* B = (const float*)d_in[2];
    float* Y = (float*)d_out;
    // 768 persistent blocks = 3 per CU (LDS 3x27.2KB, VGPR capped by launch_bounds(256,3))
    conv3x3_kernel<<<dim3(768), dim3(256), 0, stream>>>(X, W, B, Y);
}